// Round 7
// baseline (273.795 us; speedup 1.0000x reference)
//
#include <hip/hip_runtime.h>

#define HID 64
#define NPB 256   // nodes per bucket (bucket = dst >> 8)

__device__ inline float bf2f(unsigned short u) {
  return __uint_as_float((unsigned int)u << 16);
}
__device__ inline unsigned short f2bf(float f) {
  unsigned int u = __float_as_uint(f);
  u += 0x7fff + ((u >> 16) & 1);  // round-to-nearest-even
  return (unsigned short)(u >> 16);
}
__device__ inline float readlane_f(float v, int l) {
  return __int_as_float(__builtin_amdgcn_readlane(__float_as_int(v), l));
}

// ---- S1: per-block LDS histogram over buckets + padded-line global reservation ----
__global__ __launch_bounds__(256) void k_hist(const int* __restrict__ dst,
                                              unsigned int* __restrict__ bucketCnt,  // B*16 padded
                                              unsigned int* __restrict__ blockBase,  // [B][B]
                                              int B, int ept, int nE) {
  __shared__ unsigned int hist[512];
  for (int c = threadIdx.x; c < B; c += 256) hist[c] = 0;
  __syncthreads();
  int base = blockIdx.x * 256 * ept;
  for (int i = 0; i < ept; ++i) {
    int e = base + i * 256 + threadIdx.x;
    if (e < nE) atomicAdd(&hist[(unsigned)dst[e] >> 8], 1u);
  }
  __syncthreads();
  for (int c = threadIdx.x; c < B; c += 256) {
    unsigned int h = hist[c];
    unsigned int b = 0;
    if (h) b = atomicAdd(&bucketCnt[c * 16], h);  // 64B-padded: serial only per line
    blockBase[(size_t)blockIdx.x * B + c] = b;
  }
}

// ---- S2: exclusive scan of bucket totals (B <= 512) ----
__global__ __launch_bounds__(512) void k_bscan(const unsigned int* __restrict__ bucketCnt,
                                               int* __restrict__ bucketStart,
                                               int* __restrict__ rowStart,
                                               int B, int n, int nE) {
  __shared__ int s[512];
  int v = (threadIdx.x < (unsigned)B) ? (int)bucketCnt[threadIdx.x * 16] : 0;
  s[threadIdx.x] = v;
  __syncthreads();
  for (int o = 1; o < 512; o <<= 1) {
    int t = (threadIdx.x >= (unsigned)o) ? s[threadIdx.x - o] : 0;
    __syncthreads();
    s[threadIdx.x] += t;
    __syncthreads();
  }
  if (threadIdx.x < (unsigned)B) bucketStart[threadIdx.x] = s[threadIdx.x] - v;
  if (threadIdx.x == 0) { bucketStart[B] = nE; rowStart[n] = nE; }
}

// ---- S3: scatter edges into bucket regions via LDS cursors ----
// record: {src | dLoc<<24, ew_bits}  (src < 2^24)
__global__ __launch_bounds__(256) void k_bucket(const int* __restrict__ src,
                                                const int* __restrict__ dst,
                                                const float* __restrict__ ew,
                                                const int* __restrict__ bucketStart,
                                                const unsigned int* __restrict__ blockBase,
                                                int2* __restrict__ e8,
                                                int B, int ept, int nE) {
  __shared__ int cursor[512];
  for (int c = threadIdx.x; c < B; c += 256)
    cursor[c] = bucketStart[c] + (int)blockBase[(size_t)blockIdx.x * B + c];
  __syncthreads();
  int base = blockIdx.x * 256 * ept;
  for (int i = 0; i < ept; ++i) {
    int e = base + i * 256 + threadIdx.x;
    if (e < nE) {
      int d = dst[e];
      int slot = atomicAdd(&cursor[d >> 8], 1);
      e8[slot] = make_int2(src[e] | ((d & 255) << 24), __float_as_int(ew[e]));
    }
  }
}

// ---- S4a: per-bucket degrees via LDS float atomics; dinv coalesced ----
__global__ __launch_bounds__(NPB) void k_deg(const int2* __restrict__ e8,
                                             const int* __restrict__ bucketStart,
                                             float* __restrict__ dinv, int n) {
  __shared__ float deg[NPB];
  deg[threadIdx.x] = 1.0f;  // self-loop weight
  __syncthreads();
  int c = blockIdx.x;
  int i0 = bucketStart[c], i1 = bucketStart[c + 1];
  for (int i = i0 + threadIdx.x; i < i1; i += NPB) {
    int2 r = e8[i];
    atomicAdd(&deg[(unsigned)r.x >> 24], __int_as_float(r.y));
  }
  __syncthreads();
  int g = c * NPB + threadIdx.x;
  if (g < n) dinv[g] = rsqrtf(deg[threadIdx.x]);
}

// ---- S4b: per-bucket LDS counting sort -> rowStart + edges{src, norm} ----
__global__ __launch_bounds__(NPB) void k_sortfill(const int2* __restrict__ e8,
                                                  const int* __restrict__ bucketStart,
                                                  const float* __restrict__ dinv,
                                                  int* __restrict__ rowStart,
                                                  int2* __restrict__ edges, int n) {
  __shared__ int cnt[NPB];
  __shared__ int s[NPB];
  cnt[threadIdx.x] = 0;
  __syncthreads();
  int c = blockIdx.x;
  int i0 = bucketStart[c], i1 = bucketStart[c + 1];
  for (int i = i0 + threadIdx.x; i < i1; i += NPB)
    atomicAdd(&cnt[(unsigned)e8[i].x >> 24], 1);
  __syncthreads();
  int v = cnt[threadIdx.x];
  s[threadIdx.x] = v;
  __syncthreads();
  for (int o = 1; o < NPB; o <<= 1) {
    int t = (threadIdx.x >= (unsigned)o) ? s[threadIdx.x - o] : 0;
    __syncthreads();
    s[threadIdx.x] += t;
    __syncthreads();
  }
  int rowBase = i0 + s[threadIdx.x] - v;  // absolute exclusive start for my node
  int g = c * NPB + threadIdx.x;
  if (g < n) rowStart[g] = rowBase;
  __syncthreads();
  cnt[threadIdx.x] = rowBase;    // reuse as cursor
  __syncthreads();
  for (int i = i0 + threadIdx.x; i < i1; i += NPB) {
    int2 r = e8[i];
    int l = (unsigned)r.x >> 24;
    int sn = r.x & 0xFFFFFF;
    int pos = atomicAdd(&cnt[l], 1);
    float norm = dinv[sn] * __int_as_float(r.y) * dinv[c * NPB + l];
    edges[pos] = make_int2(sn, __float_as_int(norm));
  }
}

// ---- dense 64x64 projection (layer 1 only): lane j holds W column j ----
__global__ __launch_bounds__(256) void k_gemm64(const float* __restrict__ X,
                                                const float* __restrict__ W,
                                                unsigned short* __restrict__ Out, int n) {
  int lane = threadIdx.x & 63;
  float Wc[HID];
#pragma unroll
  for (int k = 0; k < HID; ++k) Wc[k] = W[k * HID + lane];
  int wave = (blockIdx.x * 256 + threadIdx.x) >> 6;
  int nwaves = (gridDim.x * 256) >> 6;
  for (int node = wave; node < n; node += nwaves) {
    float xl = X[(size_t)node * HID + lane];
    float a0 = 0.f, a1 = 0.f;
#pragma unroll
    for (int k = 0; k < HID; k += 2) {
      a0 = fmaf(readlane_f(xl, k), Wc[k], a0);
      a1 = fmaf(readlane_f(xl, k + 1), Wc[k + 1], a1);
    }
    Out[(size_t)node * HID + lane] = f2bf(a0 + a1);
  }
}

// ---- CSR aggregate, unroll-16 MLP. MODE 1: fused epilogue (h=relu(agg+b) then
// g=h@W2 via LDS W2 + readlane, bf16 out). MODE 0: plain agg + bias, f32 out. ----
template <int MODE>
__global__ __launch_bounds__(256) void k_aggregate(const int2* __restrict__ edges,
                                                   const int* __restrict__ rowStart,
                                                   const float* __restrict__ dinv,
                                                   const unsigned short* __restrict__ Hin,
                                                   const float* __restrict__ bias,
                                                   const float* __restrict__ W2,
                                                   void* __restrict__ outp, int n) {
  __shared__ float W2s[MODE ? HID * HID : 1];
  if (MODE) {
    for (int idx = threadIdx.x; idx < HID * HID; idx += 256) W2s[idx] = W2[idx];
    __syncthreads();
  }
  int j = threadIdx.x & 63;
  int node = __builtin_amdgcn_readfirstlane((blockIdx.x * 256 + threadIdx.x) >> 6);
  if (node >= n) return;
  int e0 = rowStart[node];
  int e1 = rowStart[node + 1];
  int last = e1 - 1;
  float di = dinv[node];
  float a[8];
  a[0] = di * di * bf2f(Hin[(size_t)node * HID + j]);
#pragma unroll
  for (int k = 1; k < 8; ++k) a[k] = 0.f;
  for (int e = e0; e < e1; e += 16) {
    float hv[16], nv[16];
#pragma unroll
    for (int k = 0; k < 16; ++k) {           // issue all 16 gathers first
      int idx = (e + k < e1) ? e + k : last;
      int2 r = edges[idx];
      hv[k] = bf2f(Hin[(size_t)r.x * HID + j]);
      nv[k] = (e + k < e1) ? __int_as_float(r.y) : 0.f;
    }
#pragma unroll
    for (int k = 0; k < 16; ++k) a[k & 7] = fmaf(nv[k], hv[k], a[k & 7]);
  }
  float acc = (((a[0] + a[1]) + (a[2] + a[3])) + ((a[4] + a[5]) + (a[6] + a[7]))) + bias[j];
  if (MODE) {
    float h = fmaxf(acc, 0.f);               // relu (layer 1)
    float g0 = 0.f, g1 = 0.f;                // g = h @ W2, lane j = out channel
#pragma unroll
    for (int k = 0; k < HID; k += 2) {
      g0 = fmaf(readlane_f(h, k), W2s[k * HID + j], g0);
      g1 = fmaf(readlane_f(h, k + 1), W2s[(k + 1) * HID + j], g1);
    }
    ((unsigned short*)outp)[(size_t)node * HID + j] = f2bf(g0 + g1);
  } else {
    ((float*)outp)[(size_t)node * HID + j] = acc;
  }
}

extern "C" void kernel_launch(void* const* d_in, const int* in_sizes, int n_in,
                              void* d_out, int out_size, void* d_ws, size_t ws_size,
                              hipStream_t stream) {
  const float* x  = (const float*)d_in[0];
  const int*   ei = (const int*)d_in[1];
  const float* ew = (const float*)d_in[2];
  const float* W1 = (const float*)d_in[3];
  const float* b1 = (const float*)d_in[4];
  const float* W2 = (const float*)d_in[5];
  const float* b2 = (const float*)d_in[6];
  float* out = (float*)d_out;

  const int n  = in_sizes[0] / HID;   // 100000
  const int nE = in_sizes[2];         // 1000000
  const int* src = ei;
  const int* dst = ei + nE;

  const int B   = (n + NPB - 1) / NPB;                // 391 buckets
  const int ept = (nE + B * 256 - 1) / (B * 256);     // edges per thread in S1/S3

  auto align512 = [](size_t v) { return (v + 511) & ~(size_t)511; };
  char* ws = (char*)d_ws;
  size_t off = 0;
  float* dinv        = (float*)(ws + off); off += align512((size_t)n * 4);
  int*   rowStart    = (int*)  (ws + off); off += align512((size_t)(n + 1) * 4);
  unsigned int* bucketCnt = (unsigned int*)(ws + off); off += align512((size_t)B * 16 * 4);
  int*   bucketStart = (int*)  (ws + off); off += align512((size_t)(B + 1) * 4);
  int2*  edges       = (int2*) (ws + off); off += align512((size_t)nE * 8);
  unsigned short* bufA = (unsigned short*)(ws + off); off += align512((size_t)n * HID * 2);
  unsigned short* bufB = (unsigned short*)(ws + off);

  // blockBase (B*B*4 ~ 612KB) + e8 (nE*8 = 8MB) alias onto bufA (12.8MB):
  // both dead before gemm1 writes bufA.
  unsigned int* blockBase = (unsigned int*)bufA;
  int2* e8 = (int2*)((char*)bufA + align512((size_t)B * B * 4));

  const int featBlocks = (n * HID + 255) / 256;

  // ---- CSR build: atomic-free counting sort by dst>>8 ----
  hipMemsetAsync(bucketCnt, 0, (size_t)B * 16 * 4, stream);
  k_hist<<<B, 256, 0, stream>>>(dst, bucketCnt, blockBase, B, ept, nE);
  k_bscan<<<1, 512, 0, stream>>>(bucketCnt, bucketStart, rowStart, B, n, nE);
  k_bucket<<<B, 256, 0, stream>>>(src, dst, ew, bucketStart, blockBase, e8, B, ept, nE);
  k_deg<<<B, NPB, 0, stream>>>(e8, bucketStart, dinv, n);
  k_sortfill<<<B, NPB, 0, stream>>>(e8, bucketStart, dinv, rowStart, edges, n);

  // ---- layer 1 projection ----
  k_gemm64<<<2048, 256, 0, stream>>>(x, W1, bufA, n);
  // ---- layer 1 aggregate + relu + fused layer-2 projection ----
  k_aggregate<1><<<featBlocks, 256, 0, stream>>>(edges, rowStart, dinv, bufA, b1, W2, bufB, n);
  // ---- layer 2 aggregate (final, f32 out) ----
  k_aggregate<0><<<featBlocks, 256, 0, stream>>>(edges, rowStart, dinv, bufB, b2, nullptr, out, n);
}

// Round 8
// 262.159 us; speedup vs baseline: 1.0444x; 1.0444x over previous
//
#include <hip/hip_runtime.h>

#define HID 64
#define NPB 256   // nodes per bucket (bucket = dst >> 8)

__device__ inline float bf2f(unsigned short u) {
  return __uint_as_float((unsigned int)u << 16);
}
__device__ inline unsigned short f2bf(float f) {
  unsigned int u = __float_as_uint(f);
  u += 0x7fff + ((u >> 16) & 1);  // round-to-nearest-even
  return (unsigned short)(u >> 16);
}
__device__ inline float readlane_f(float v, int l) {
  return __int_as_float(__builtin_amdgcn_readlane(__float_as_int(v), l));
}

// ---- S1: per-block LDS histogram over buckets + padded-line global reservation ----
__global__ __launch_bounds__(256) void k_hist(const int* __restrict__ dst,
                                              unsigned int* __restrict__ bucketCnt,  // B*16 padded
                                              unsigned int* __restrict__ blockBase,  // [B][B]
                                              int B, int ept, int nE) {
  __shared__ unsigned int hist[512];
  for (int c = threadIdx.x; c < B; c += 256) hist[c] = 0;
  __syncthreads();
  int base = blockIdx.x * 256 * ept;
  for (int i = 0; i < ept; ++i) {
    int e = base + i * 256 + threadIdx.x;
    if (e < nE) atomicAdd(&hist[(unsigned)dst[e] >> 8], 1u);
  }
  __syncthreads();
  for (int c = threadIdx.x; c < B; c += 256) {
    unsigned int h = hist[c];
    unsigned int b = 0;
    if (h) b = atomicAdd(&bucketCnt[c * 16], h);  // 64B-padded: serial only per line
    blockBase[(size_t)blockIdx.x * B + c] = b;
  }
}

// ---- S2: exclusive scan of bucket totals (B <= 512) ----
__global__ __launch_bounds__(512) void k_bscan(const unsigned int* __restrict__ bucketCnt,
                                               int* __restrict__ bucketStart,
                                               int* __restrict__ rowStart,
                                               int B, int n, int nE) {
  __shared__ int s[512];
  int v = (threadIdx.x < (unsigned)B) ? (int)bucketCnt[threadIdx.x * 16] : 0;
  s[threadIdx.x] = v;
  __syncthreads();
  for (int o = 1; o < 512; o <<= 1) {
    int t = (threadIdx.x >= (unsigned)o) ? s[threadIdx.x - o] : 0;
    __syncthreads();
    s[threadIdx.x] += t;
    __syncthreads();
  }
  if (threadIdx.x < (unsigned)B) bucketStart[threadIdx.x] = s[threadIdx.x] - v;
  if (threadIdx.x == 0) { bucketStart[B] = nE; rowStart[n] = nE; }
}

// ---- S3: scatter edges into bucket regions via LDS cursors ----
// record: {src | dLoc<<24, ew_bits}  (src < 2^24)
__global__ __launch_bounds__(256) void k_bucket(const int* __restrict__ src,
                                                const int* __restrict__ dst,
                                                const float* __restrict__ ew,
                                                const int* __restrict__ bucketStart,
                                                const unsigned int* __restrict__ blockBase,
                                                int2* __restrict__ e8,
                                                int B, int ept, int nE) {
  __shared__ int cursor[512];
  for (int c = threadIdx.x; c < B; c += 256)
    cursor[c] = bucketStart[c] + (int)blockBase[(size_t)blockIdx.x * B + c];
  __syncthreads();
  int base = blockIdx.x * 256 * ept;
  for (int i = 0; i < ept; ++i) {
    int e = base + i * 256 + threadIdx.x;
    if (e < nE) {
      int d = dst[e];
      int slot = atomicAdd(&cursor[d >> 8], 1);
      e8[slot] = make_int2(src[e] | ((d & 255) << 24), __float_as_int(ew[e]));
    }
  }
}

// ---- S4: per-bucket deg + count + scan in ONE e8 pass -> dinv + rowStart ----
__global__ __launch_bounds__(NPB) void k_degcnt(const int2* __restrict__ e8,
                                                const int* __restrict__ bucketStart,
                                                float* __restrict__ dinv,
                                                int* __restrict__ rowStart, int n) {
  __shared__ float deg[NPB];
  __shared__ int cnt[NPB];
  __shared__ int s[NPB];
  deg[threadIdx.x] = 1.0f;  // self-loop weight
  cnt[threadIdx.x] = 0;
  __syncthreads();
  int c = blockIdx.x;
  int i0 = bucketStart[c], i1 = bucketStart[c + 1];
  for (int i = i0 + threadIdx.x; i < i1; i += NPB) {
    int2 r = e8[i];
    int l = (unsigned)r.x >> 24;
    atomicAdd(&deg[l], __int_as_float(r.y));
    atomicAdd(&cnt[l], 1);
  }
  __syncthreads();
  int v = cnt[threadIdx.x];
  s[threadIdx.x] = v;
  __syncthreads();
  for (int o = 1; o < NPB; o <<= 1) {
    int t = (threadIdx.x >= (unsigned)o) ? s[threadIdx.x - o] : 0;
    __syncthreads();
    s[threadIdx.x] += t;
    __syncthreads();
  }
  int g = c * NPB + threadIdx.x;
  if (g < n) {
    rowStart[g] = i0 + s[threadIdx.x] - v;  // absolute exclusive start
    dinv[g] = rsqrtf(deg[threadIdx.x]);
  }
}

// ---- S5: fill pass only: cursors from rowStart; dst-dinv staged in LDS ----
__global__ __launch_bounds__(NPB) void k_fill2(const int2* __restrict__ e8,
                                               const int* __restrict__ bucketStart,
                                               const float* __restrict__ dinv,
                                               const int* __restrict__ rowStart,
                                               int2* __restrict__ edges, int n) {
  __shared__ int cursor[NPB];
  __shared__ float ddst[NPB];
  int c = blockIdx.x;
  int i0 = bucketStart[c], i1 = bucketStart[c + 1];
  int g = c * NPB + threadIdx.x;
  cursor[threadIdx.x] = (g < n) ? rowStart[g] : i1;
  ddst[threadIdx.x] = (g < n) ? dinv[g] : 0.f;
  __syncthreads();
  for (int i = i0 + threadIdx.x; i < i1; i += NPB) {
    int2 r = e8[i];
    int l = (unsigned)r.x >> 24;
    int sn = r.x & 0xFFFFFF;
    int pos = atomicAdd(&cursor[l], 1);
    float norm = dinv[sn] * __int_as_float(r.y) * ddst[l];
    edges[pos] = make_int2(sn, __float_as_int(norm));
  }
}

// ---- dense 64x64 projection: lane j holds W column j; readlane-broadcast x ----
template <typename TI>
__global__ __launch_bounds__(256) void k_gemm64(const TI* __restrict__ X,
                                                const float* __restrict__ W,
                                                unsigned short* __restrict__ Out, int n) {
  int lane = threadIdx.x & 63;
  float Wc[HID];
#pragma unroll
  for (int k = 0; k < HID; ++k) Wc[k] = W[k * HID + lane];
  int wave = (blockIdx.x * 256 + threadIdx.x) >> 6;
  int nwaves = (gridDim.x * 256) >> 6;
  for (int node = wave; node < n; node += nwaves) {
    TI raw = X[(size_t)node * HID + lane];
    float xl;
    if (sizeof(TI) == 2) xl = bf2f((unsigned short)raw);
    else xl = (float)raw;
    float a0 = 0.f, a1 = 0.f;
#pragma unroll
    for (int k = 0; k < HID; k += 2) {
      a0 = fmaf(readlane_f(xl, k), Wc[k], a0);
      a1 = fmaf(readlane_f(xl, k + 1), Wc[k + 1], a1);
    }
    Out[(size_t)node * HID + lane] = f2bf(a0 + a1);
  }
}

// ---- CSR aggregate: 2 nodes per wave (half-wave = node, lane covers 2 channels
// via packed bf16x2). Unroll-8 per stream -> 16 rows in flight per wave. ----
template <int OUT_BF16>
__global__ __launch_bounds__(256) void k_agg2(const int2* __restrict__ edges,
                                              const int* __restrict__ rowStart,
                                              const float* __restrict__ dinv,
                                              const unsigned int* __restrict__ H2,
                                              const float* __restrict__ bias,
                                              void* __restrict__ outp, int n, int nwaves) {
  int gwave = (blockIdx.x * 256 + threadIdx.x) >> 6;
  int lane = threadIdx.x & 63;
  int half = lane >> 5;
  int hl = lane & 31;
  int node = gwave * 2 + half;
  if (node >= n) return;
  int e0 = rowStart[node];
  int e1 = rowStart[node + 1];
  float di = dinv[node];
  unsigned int su = H2[(size_t)node * 32 + hl];
  float dd = di * di;
  float ax = dd * __uint_as_float(su << 16);
  float ay = dd * __uint_as_float(su & 0xffff0000u);
  for (int e = e0; e < e1; e += 8) {
    int last = e1 - 1;
    float hx[8], hy[8], nm[8];
#pragma unroll
    for (int k = 0; k < 8; ++k) {           // 8 edge + 8 row loads per stream in flight
      int idx = (e + k < e1) ? e + k : last;
      int2 r = edges[idx];
      unsigned int u = H2[(size_t)(unsigned)r.x * 32u + hl];
      hx[k] = __uint_as_float(u << 16);
      hy[k] = __uint_as_float(u & 0xffff0000u);
      nm[k] = (e + k < e1) ? __int_as_float(r.y) : 0.f;
    }
#pragma unroll
    for (int k = 0; k < 8; ++k) {
      ax = fmaf(nm[k], hx[k], ax);
      ay = fmaf(nm[k], hy[k], ay);
    }
  }
  float2 bv = ((const float2*)bias)[hl];
  ax += bv.x;
  ay += bv.y;
  if (OUT_BF16) {
    ax = fmaxf(ax, 0.f);                    // relu (layer 1)
    ay = fmaxf(ay, 0.f);
    unsigned int lo = f2bf(ax), hi = f2bf(ay);
    ((unsigned int*)outp)[(size_t)node * 32 + hl] = lo | (hi << 16);
  } else {
    float2 o;
    o.x = ax;
    o.y = ay;
    ((float2*)outp)[(size_t)node * 32 + hl] = o;
  }
}

extern "C" void kernel_launch(void* const* d_in, const int* in_sizes, int n_in,
                              void* d_out, int out_size, void* d_ws, size_t ws_size,
                              hipStream_t stream) {
  const float* x  = (const float*)d_in[0];
  const int*   ei = (const int*)d_in[1];
  const float* ew = (const float*)d_in[2];
  const float* W1 = (const float*)d_in[3];
  const float* b1 = (const float*)d_in[4];
  const float* W2 = (const float*)d_in[5];
  const float* b2 = (const float*)d_in[6];
  float* out = (float*)d_out;

  const int n  = in_sizes[0] / HID;   // 100000
  const int nE = in_sizes[2];         // 1000000
  const int* src = ei;
  const int* dst = ei + nE;

  const int B   = (n + NPB - 1) / NPB;                // 391 buckets
  const int ept = (nE + B * 256 - 1) / (B * 256);     // edges per thread in S1/S3

  auto align512 = [](size_t v) { return (v + 511) & ~(size_t)511; };
  char* ws = (char*)d_ws;
  size_t off = 0;
  float* dinv        = (float*)(ws + off); off += align512((size_t)n * 4);
  int*   rowStart    = (int*)  (ws + off); off += align512((size_t)(n + 1) * 4);
  unsigned int* bucketCnt = (unsigned int*)(ws + off); off += align512((size_t)B * 16 * 4);
  int*   bucketStart = (int*)  (ws + off); off += align512((size_t)(B + 1) * 4);
  int2*  edges       = (int2*) (ws + off); off += align512((size_t)nE * 8);
  unsigned short* bufA = (unsigned short*)(ws + off); off += align512((size_t)n * HID * 2);
  unsigned short* bufB = (unsigned short*)(ws + off);

  // blockBase (B*B*4 ~ 612KB) + e8 (nE*8 = 8MB) alias onto bufA (12.8MB):
  // both dead before gemm1 writes bufA.
  unsigned int* blockBase = (unsigned int*)bufA;
  int2* e8 = (int2*)((char*)bufA + align512((size_t)B * B * 4));

  const int nwaves = (n + 1) / 2;                       // 2 nodes per wave
  const int aggBlocks = (nwaves * 64 + 255) / 256;      // 12500

  // ---- CSR build: atomic-free counting sort by dst>>8 ----
  hipMemsetAsync(bucketCnt, 0, (size_t)B * 16 * 4, stream);
  k_hist<<<B, 256, 0, stream>>>(dst, bucketCnt, blockBase, B, ept, nE);
  k_bscan<<<1, 512, 0, stream>>>(bucketCnt, bucketStart, rowStart, B, n, nE);
  k_bucket<<<B, 256, 0, stream>>>(src, dst, ew, bucketStart, blockBase, e8, B, ept, nE);
  k_degcnt<<<B, NPB, 0, stream>>>(e8, bucketStart, dinv, rowStart, n);
  k_fill2<<<B, NPB, 0, stream>>>(e8, bucketStart, dinv, rowStart, edges, n);

  // ---- layer 1 ----
  k_gemm64<float><<<2048, 256, 0, stream>>>(x, W1, bufA, n);
  k_agg2<1><<<aggBlocks, 256, 0, stream>>>(edges, rowStart, dinv,
                                           (const unsigned int*)bufA, b1, bufB, n, nwaves);

  // ---- layer 2 ----
  k_gemm64<unsigned short><<<2048, 256, 0, stream>>>(bufB, W2, bufA, n);
  k_agg2<0><<<aggBlocks, 256, 0, stream>>>(edges, rowStart, dinv,
                                           (const unsigned int*)bufA, b2, out, n, nwaves);
}

// Round 9
// 241.327 us; speedup vs baseline: 1.1345x; 1.0863x over previous
//
#include <hip/hip_runtime.h>

#define HID 64
#define NPB 256   // nodes per bucket (bucket = dst >> 8)

__device__ inline float bf2f(unsigned short u) {
  return __uint_as_float((unsigned int)u << 16);
}
__device__ inline unsigned short f2bf(float f) {
  unsigned int u = __float_as_uint(f);
  u += 0x7fff + ((u >> 16) & 1);  // round-to-nearest-even
  return (unsigned short)(u >> 16);
}
__device__ inline float readlane_f(float v, int l) {
  return __int_as_float(__builtin_amdgcn_readlane(__float_as_int(v), l));
}

// ---- S1: per-block LDS histogram over buckets + padded-line global reservation ----
__global__ __launch_bounds__(256) void k_hist(const int* __restrict__ dst,
                                              unsigned int* __restrict__ bucketCnt,  // B*16 padded
                                              unsigned int* __restrict__ blockBase,  // [B][B]
                                              int B, int ept, int nE) {
  __shared__ unsigned int hist[512];
  for (int c = threadIdx.x; c < B; c += 256) hist[c] = 0;
  __syncthreads();
  int base = blockIdx.x * 256 * ept;
  for (int i = 0; i < ept; ++i) {
    int e = base + i * 256 + threadIdx.x;
    if (e < nE) atomicAdd(&hist[(unsigned)dst[e] >> 8], 1u);
  }
  __syncthreads();
  for (int c = threadIdx.x; c < B; c += 256) {
    unsigned int h = hist[c];
    unsigned int b = 0;
    if (h) b = atomicAdd(&bucketCnt[c * 16], h);  // 64B-padded: serial only per line
    blockBase[(size_t)blockIdx.x * B + c] = b;
  }
}

// ---- S2: exclusive scan of bucket totals (B <= 512) ----
__global__ __launch_bounds__(512) void k_bscan(const unsigned int* __restrict__ bucketCnt,
                                               int* __restrict__ bucketStart,
                                               int* __restrict__ rowStart,
                                               int B, int n, int nE) {
  __shared__ int s[512];
  int v = (threadIdx.x < (unsigned)B) ? (int)bucketCnt[threadIdx.x * 16] : 0;
  s[threadIdx.x] = v;
  __syncthreads();
  for (int o = 1; o < 512; o <<= 1) {
    int t = (threadIdx.x >= (unsigned)o) ? s[threadIdx.x - o] : 0;
    __syncthreads();
    s[threadIdx.x] += t;
    __syncthreads();
  }
  if (threadIdx.x < (unsigned)B) bucketStart[threadIdx.x] = s[threadIdx.x] - v;
  if (threadIdx.x == 0) { bucketStart[B] = nE; rowStart[n] = nE; }
}

// ---- S3: scatter edges into bucket regions via LDS cursors ----
// record: {src | dLoc<<24, ew_bits}  (src < 2^24)
__global__ __launch_bounds__(256) void k_bucket(const int* __restrict__ src,
                                                const int* __restrict__ dst,
                                                const float* __restrict__ ew,
                                                const int* __restrict__ bucketStart,
                                                const unsigned int* __restrict__ blockBase,
                                                int2* __restrict__ e8,
                                                int B, int ept, int nE) {
  __shared__ int cursor[512];
  for (int c = threadIdx.x; c < B; c += 256)
    cursor[c] = bucketStart[c] + (int)blockBase[(size_t)blockIdx.x * B + c];
  __syncthreads();
  int base = blockIdx.x * 256 * ept;
  for (int i = 0; i < ept; ++i) {
    int e = base + i * 256 + threadIdx.x;
    if (e < nE) {
      int d = dst[e];
      int slot = atomicAdd(&cursor[d >> 8], 1);
      e8[slot] = make_int2(src[e] | ((d & 255) << 24), __float_as_int(ew[e]));
    }
  }
}

// ---- S4: FUSED deg + count + scan + fill, one kernel, single global e8 pass ----
// edges record: {src, ew * dinv[dst]} — the dinv[src] factor is folded into the
// feature table (gemm writes Hs = dinv*h), removing the cross-block dependency.
__global__ __launch_bounds__(NPB) void k_degfill(const int2* __restrict__ e8,
                                                 const int* __restrict__ bucketStart,
                                                 float* __restrict__ dinv,
                                                 int* __restrict__ rowStart,
                                                 int2* __restrict__ edges, int n) {
  __shared__ float deg[NPB];
  __shared__ int cnt[NPB];
  __shared__ int s[NPB];
  deg[threadIdx.x] = 1.0f;  // self-loop weight
  cnt[threadIdx.x] = 0;
  __syncthreads();
  int c = blockIdx.x;
  int i0 = bucketStart[c], i1 = bucketStart[c + 1];
  for (int i = i0 + threadIdx.x; i < i1; i += NPB) {
    int2 r = e8[i];
    int l = (unsigned)r.x >> 24;
    atomicAdd(&deg[l], __int_as_float(r.y));
    atomicAdd(&cnt[l], 1);
  }
  __syncthreads();
  int v = cnt[threadIdx.x];
  s[threadIdx.x] = v;
  __syncthreads();
  for (int o = 1; o < NPB; o <<= 1) {
    int t = (threadIdx.x >= (unsigned)o) ? s[threadIdx.x - o] : 0;
    __syncthreads();
    s[threadIdx.x] += t;
    __syncthreads();
  }
  int rowBase = i0 + s[threadIdx.x] - v;
  float di = rsqrtf(deg[threadIdx.x]);
  int g = c * NPB + threadIdx.x;
  if (g < n) {
    rowStart[g] = rowBase;
    dinv[g] = di;
  }
  __syncthreads();             // all reads of deg/cnt/s done
  cnt[threadIdx.x] = rowBase;  // reuse as cursor
  deg[threadIdx.x] = di;       // reuse as ddst
  __syncthreads();
  for (int i = i0 + threadIdx.x; i < i1; i += NPB) {  // bucket region is L1/L2-hot
    int2 r = e8[i];
    int l = (unsigned)r.x >> 24;
    int sn = r.x & 0xFFFFFF;
    int pos = atomicAdd(&cnt[l], 1);
    float norm = __int_as_float(r.y) * deg[l];  // ew * dinv[dst]
    edges[pos] = make_int2(sn, __float_as_int(norm));
  }
}

// ---- dense 64x64 projection, output scaled by dinv: Hs = dinv[node]*(X@W) ----
template <typename TI>
__global__ __launch_bounds__(256) void k_gemm64(const TI* __restrict__ X,
                                                const float* __restrict__ W,
                                                const float* __restrict__ dinv,
                                                unsigned short* __restrict__ Out, int n) {
  int lane = threadIdx.x & 63;
  float Wc[HID];
#pragma unroll
  for (int k = 0; k < HID; ++k) Wc[k] = W[k * HID + lane];
  int wave = (blockIdx.x * 256 + threadIdx.x) >> 6;
  int nwaves = (gridDim.x * 256) >> 6;
  for (int node = wave; node < n; node += nwaves) {
    TI raw = X[(size_t)node * HID + lane];
    float xl;
    if (sizeof(TI) == 2) xl = bf2f((unsigned short)raw);
    else xl = (float)raw;
    float a0 = 0.f, a1 = 0.f;
#pragma unroll
    for (int k = 0; k < HID; k += 2) {
      a0 = fmaf(readlane_f(xl, k), Wc[k], a0);
      a1 = fmaf(readlane_f(xl, k + 1), Wc[k + 1], a1);
    }
    Out[(size_t)node * HID + lane] = f2bf((a0 + a1) * dinv[node]);
  }
}

// ---- CSR aggregate: 4 nodes per wave (16-lane quarter = node, lane covers 4
// channels via one dwordx2 = 4 bf16). One gather instr serves 4 edge rows. ----
template <int OUT_BF16>
__global__ __launch_bounds__(256) void k_agg4(const int2* __restrict__ edges,
                                              const int* __restrict__ rowStart,
                                              const float* __restrict__ dinv,
                                              const uint2* __restrict__ H4,   // Hs as 16 x uint2 per node
                                              const float* __restrict__ bias,
                                              void* __restrict__ outp, int n) {
  int gwave = (blockIdx.x * 256 + threadIdx.x) >> 6;
  int lane = threadIdx.x & 63;
  int q = lane >> 4;    // quarter index: which of 4 nodes
  int ql = lane & 15;   // lane within quarter: channels 4*ql..4*ql+3
  int node = gwave * 4 + q;
  if (node >= n) return;
  int e0 = rowStart[node];
  int e1 = rowStart[node + 1];
  float di = dinv[node];
  uint2 su = H4[(size_t)node * 16 + ql];
  // self-loop: dinv * Hs[node]  (Hs already carries one dinv factor)
  float a0 = di * __uint_as_float(su.x << 16);
  float a1 = di * __uint_as_float(su.x & 0xffff0000u);
  float a2 = di * __uint_as_float(su.y << 16);
  float a3 = di * __uint_as_float(su.y & 0xffff0000u);
  for (int e = e0; e < e1; e += 8) {
    int last = e1 - 1;
    uint2 hv[8];
    float nm[8];
#pragma unroll
    for (int k = 0; k < 8; ++k) {   // 8 edge loads + 8 row gathers in flight
      int idx = (e + k < e1) ? e + k : last;
      int2 r = edges[idx];
      hv[k] = H4[(size_t)(unsigned)r.x * 16u + ql];
      nm[k] = (e + k < e1) ? __int_as_float(r.y) : 0.f;
    }
#pragma unroll
    for (int k = 0; k < 8; ++k) {
      a0 = fmaf(nm[k], __uint_as_float(hv[k].x << 16), a0);
      a1 = fmaf(nm[k], __uint_as_float(hv[k].x & 0xffff0000u), a1);
      a2 = fmaf(nm[k], __uint_as_float(hv[k].y << 16), a2);
      a3 = fmaf(nm[k], __uint_as_float(hv[k].y & 0xffff0000u), a3);
    }
  }
  float4 bv = ((const float4*)bias)[ql];
  a0 += bv.x; a1 += bv.y; a2 += bv.z; a3 += bv.w;
  if (OUT_BF16) {
    a0 = fmaxf(a0, 0.f); a1 = fmaxf(a1, 0.f);   // relu (layer 1)
    a2 = fmaxf(a2, 0.f); a3 = fmaxf(a3, 0.f);
    uint2 o;
    o.x = (unsigned)f2bf(a0) | ((unsigned)f2bf(a1) << 16);
    o.y = (unsigned)f2bf(a2) | ((unsigned)f2bf(a3) << 16);
    ((uint2*)outp)[(size_t)node * 16 + ql] = o;
  } else {
    float4 o;
    o.x = a0; o.y = a1; o.z = a2; o.w = a3;
    ((float4*)outp)[(size_t)node * 16 + ql] = o;
  }
}

extern "C" void kernel_launch(void* const* d_in, const int* in_sizes, int n_in,
                              void* d_out, int out_size, void* d_ws, size_t ws_size,
                              hipStream_t stream) {
  const float* x  = (const float*)d_in[0];
  const int*   ei = (const int*)d_in[1];
  const float* ew = (const float*)d_in[2];
  const float* W1 = (const float*)d_in[3];
  const float* b1 = (const float*)d_in[4];
  const float* W2 = (const float*)d_in[5];
  const float* b2 = (const float*)d_in[6];
  float* out = (float*)d_out;

  const int n  = in_sizes[0] / HID;   // 100000
  const int nE = in_sizes[2];         // 1000000
  const int* src = ei;
  const int* dst = ei + nE;

  const int B   = (n + NPB - 1) / NPB;                // 391 buckets
  const int ept = (nE + B * 256 - 1) / (B * 256);     // edges per thread in S1/S3

  auto align512 = [](size_t v) { return (v + 511) & ~(size_t)511; };
  char* ws = (char*)d_ws;
  size_t off = 0;
  float* dinv        = (float*)(ws + off); off += align512((size_t)n * 4);
  int*   rowStart    = (int*)  (ws + off); off += align512((size_t)(n + 1) * 4);
  unsigned int* bucketCnt = (unsigned int*)(ws + off); off += align512((size_t)B * 16 * 4);
  int*   bucketStart = (int*)  (ws + off); off += align512((size_t)(B + 1) * 4);
  int2*  edges       = (int2*) (ws + off); off += align512((size_t)nE * 8);
  unsigned short* bufA = (unsigned short*)(ws + off); off += align512((size_t)n * HID * 2);
  unsigned short* bufB = (unsigned short*)(ws + off);

  // blockBase (B*B*4 ~ 612KB) + e8 (nE*8 = 8MB) alias onto bufA (12.8MB):
  // both dead before gemm1 writes bufA.
  unsigned int* blockBase = (unsigned int*)bufA;
  int2* e8 = (int2*)((char*)bufA + align512((size_t)B * B * 4));

  const int aggBlocks = (((n + 3) / 4) * 64 + 255) / 256;   // 4 nodes per wave

  // ---- CSR build: atomic-free counting sort by dst>>8 ----
  hipMemsetAsync(bucketCnt, 0, (size_t)B * 16 * 4, stream);
  k_hist<<<B, 256, 0, stream>>>(dst, bucketCnt, blockBase, B, ept, nE);
  k_bscan<<<1, 512, 0, stream>>>(bucketCnt, bucketStart, rowStart, B, n, nE);
  k_bucket<<<B, 256, 0, stream>>>(src, dst, ew, bucketStart, blockBase, e8, B, ept, nE);
  k_degfill<<<B, NPB, 0, stream>>>(e8, bucketStart, dinv, rowStart, edges, n);

  // ---- layer 1 ----
  k_gemm64<float><<<2048, 256, 0, stream>>>(x, W1, dinv, bufA, n);
  k_agg4<1><<<aggBlocks, 256, 0, stream>>>(edges, rowStart, dinv,
                                           (const uint2*)bufA, b1, bufB, n);

  // ---- layer 2 ----
  k_gemm64<unsigned short><<<2048, 256, 0, stream>>>(bufB, W2, dinv, bufA, n);
  k_agg4<0><<<aggBlocks, 256, 0, stream>>>(edges, rowStart, dinv,
                                           (const uint2*)bufA, b2, out, n);
}

// Round 10
// 230.010 us; speedup vs baseline: 1.1904x; 1.0492x over previous
//
#include <hip/hip_runtime.h>

#define HID 64
#define NPB 256   // nodes per bucket (bucket = dst >> 8)

__device__ inline float bf2f(unsigned short u) {
  return __uint_as_float((unsigned int)u << 16);
}
__device__ inline unsigned short f2bf(float f) {
  unsigned int u = __float_as_uint(f);
  u += 0x7fff + ((u >> 16) & 1);  // round-to-nearest-even
  return (unsigned short)(u >> 16);
}
__device__ inline float bfLo(unsigned int u) { return __uint_as_float(u << 16); }
__device__ inline float bfHi(unsigned int u) { return __uint_as_float(u & 0xffff0000u); }
__device__ inline float readlane_f(float v, int l) {
  return __int_as_float(__builtin_amdgcn_readlane(__float_as_int(v), l));
}

// ---- S1: per-block LDS histogram over buckets + padded-line global reservation ----
__global__ __launch_bounds__(256) void k_hist(const int* __restrict__ dst,
                                              unsigned int* __restrict__ bucketCnt,  // B*16 padded
                                              unsigned int* __restrict__ blockBase,  // [B][B]
                                              int B, int ept, int nE) {
  __shared__ unsigned int hist[512];
  for (int c = threadIdx.x; c < B; c += 256) hist[c] = 0;
  __syncthreads();
  int base = blockIdx.x * 256 * ept;
  for (int i = 0; i < ept; ++i) {
    int e = base + i * 256 + threadIdx.x;
    if (e < nE) atomicAdd(&hist[(unsigned)dst[e] >> 8], 1u);
  }
  __syncthreads();
  for (int c = threadIdx.x; c < B; c += 256) {
    unsigned int h = hist[c];
    unsigned int b = 0;
    if (h) b = atomicAdd(&bucketCnt[c * 16], h);  // 64B-padded: serial only per line
    blockBase[(size_t)blockIdx.x * B + c] = b;
  }
}

// ---- S2: exclusive scan of bucket totals (B <= 512); also writes edge sentinels ----
__global__ __launch_bounds__(512) void k_bscan(const unsigned int* __restrict__ bucketCnt,
                                               int* __restrict__ bucketStart,
                                               int* __restrict__ rowStart,
                                               int2* __restrict__ edges,
                                               int B, int n, int nE) {
  __shared__ int s[512];
  int v = (threadIdx.x < (unsigned)B) ? (int)bucketCnt[threadIdx.x * 16] : 0;
  s[threadIdx.x] = v;
  __syncthreads();
  for (int o = 1; o < 512; o <<= 1) {
    int t = (threadIdx.x >= (unsigned)o) ? s[threadIdx.x - o] : 0;
    __syncthreads();
    s[threadIdx.x] += t;
    __syncthreads();
  }
  if (threadIdx.x < (unsigned)B) bucketStart[threadIdx.x] = s[threadIdx.x] - v;
  if (threadIdx.x == 0) { bucketStart[B] = nE; rowStart[n] = nE; }
  if (threadIdx.x < 4) edges[nE + threadIdx.x] = make_int2(0, 0);  // safe tail reads
}

// ---- S3: scatter edges into bucket regions via LDS cursors ----
// record: {src | dLoc<<24, ew_bits}  (src < 2^24)
__global__ __launch_bounds__(256) void k_bucket(const int* __restrict__ src,
                                                const int* __restrict__ dst,
                                                const float* __restrict__ ew,
                                                const int* __restrict__ bucketStart,
                                                const unsigned int* __restrict__ blockBase,
                                                int2* __restrict__ e8,
                                                int B, int ept, int nE) {
  __shared__ int cursor[512];
  for (int c = threadIdx.x; c < B; c += 256)
    cursor[c] = bucketStart[c] + (int)blockBase[(size_t)blockIdx.x * B + c];
  __syncthreads();
  int base = blockIdx.x * 256 * ept;
  for (int i = 0; i < ept; ++i) {
    int e = base + i * 256 + threadIdx.x;
    if (e < nE) {
      int d = dst[e];
      int slot = atomicAdd(&cursor[d >> 8], 1);
      e8[slot] = make_int2(src[e] | ((d & 255) << 24), __float_as_int(ew[e]));
    }
  }
}

// ---- S4: FUSED deg + count + scan + fill, one kernel, single global e8 pass ----
// edges record: {src, ew * dinv[dst]} — dinv[src] is folded into the features.
__global__ __launch_bounds__(NPB) void k_degfill(const int2* __restrict__ e8,
                                                 const int* __restrict__ bucketStart,
                                                 float* __restrict__ dinv,
                                                 int* __restrict__ rowStart,
                                                 int2* __restrict__ edges, int n) {
  __shared__ float deg[NPB];
  __shared__ int cnt[NPB];
  __shared__ int s[NPB];
  deg[threadIdx.x] = 1.0f;  // self-loop weight
  cnt[threadIdx.x] = 0;
  __syncthreads();
  int c = blockIdx.x;
  int i0 = bucketStart[c], i1 = bucketStart[c + 1];
  for (int i = i0 + threadIdx.x; i < i1; i += NPB) {
    int2 r = e8[i];
    int l = (unsigned)r.x >> 24;
    atomicAdd(&deg[l], __int_as_float(r.y));
    atomicAdd(&cnt[l], 1);
  }
  __syncthreads();
  int v = cnt[threadIdx.x];
  s[threadIdx.x] = v;
  __syncthreads();
  for (int o = 1; o < NPB; o <<= 1) {
    int t = (threadIdx.x >= (unsigned)o) ? s[threadIdx.x - o] : 0;
    __syncthreads();
    s[threadIdx.x] += t;
    __syncthreads();
  }
  int rowBase = i0 + s[threadIdx.x] - v;
  float di = rsqrtf(deg[threadIdx.x]);
  int g = c * NPB + threadIdx.x;
  if (g < n) {
    rowStart[g] = rowBase;
    dinv[g] = di;
  }
  __syncthreads();             // all reads of deg/cnt/s done
  cnt[threadIdx.x] = rowBase;  // reuse as cursor
  deg[threadIdx.x] = di;       // reuse as ddst
  __syncthreads();
  for (int i = i0 + threadIdx.x; i < i1; i += NPB) {  // bucket region is L1/L2-hot
    int2 r = e8[i];
    int l = (unsigned)r.x >> 24;
    int sn = r.x & 0xFFFFFF;
    int pos = atomicAdd(&cnt[l], 1);
    float norm = __int_as_float(r.y) * deg[l];  // ew * dinv[dst]
    edges[pos] = make_int2(sn, __float_as_int(norm));
  }
}

// ---- dense 64x64 projection, output scaled by dinv: Hs = dinv[node]*(X@W) ----
template <typename TI>
__global__ __launch_bounds__(256) void k_gemm64(const TI* __restrict__ X,
                                                const float* __restrict__ W,
                                                const float* __restrict__ dinv,
                                                unsigned short* __restrict__ Out, int n) {
  int lane = threadIdx.x & 63;
  float Wc[HID];
#pragma unroll
  for (int k = 0; k < HID; ++k) Wc[k] = W[k * HID + lane];
  int wave = (blockIdx.x * 256 + threadIdx.x) >> 6;
  int nwaves = (gridDim.x * 256) >> 6;
  for (int node = wave; node < n; node += nwaves) {
    TI raw = X[(size_t)node * HID + lane];
    float xl;
    if (sizeof(TI) == 2) xl = bf2f((unsigned short)raw);
    else xl = (float)raw;
    float a0 = 0.f, a1 = 0.f;
#pragma unroll
    for (int k = 0; k < HID; k += 2) {
      a0 = fmaf(readlane_f(xl, k), Wc[k], a0);
      a1 = fmaf(readlane_f(xl, k + 1), Wc[k + 1], a1);
    }
    Out[(size_t)node * HID + lane] = f2bf((a0 + a1) * dinv[node]);
  }
}

// ---- CSR aggregate: 8 nodes per wave (8-lane group = node, lane covers 8
// channels via one uint4 = 8 bf16 = 128B/row in ONE VMEM instr). Edge records
// loaded PAIRED via aligned int4 (2 records/instr); batch-4 loop keeps dupe
// waste ~15% on Poisson(10) degrees. ----
template <int OUT_BF16>
__global__ __launch_bounds__(256) void k_agg8(const int2* __restrict__ edges,
                                              const int* __restrict__ rowStart,
                                              const float* __restrict__ dinv,
                                              const uint4* __restrict__ H8,  // 8 x uint4 per node
                                              const float* __restrict__ bias,
                                              void* __restrict__ outp, int n) {
  int gwave = (blockIdx.x * 256 + threadIdx.x) >> 6;
  int lane = threadIdx.x & 63;
  int q = lane >> 3;    // which of 8 nodes in this wave
  int ql = lane & 7;    // channels 8*ql .. 8*ql+7
  int node = gwave * 8 + q;
  if (node >= n) return;
  int e0 = rowStart[node];
  int e1 = rowStart[node + 1];
  float di = dinv[node];
  uint4 su = H8[(size_t)node * 8 + ql];
  // self-loop: dinv * Hs[node]  (Hs already carries one dinv factor)
  float a0 = di * bfLo(su.x), a1 = di * bfHi(su.x);
  float a2 = di * bfLo(su.y), a3 = di * bfHi(su.y);
  float a4 = di * bfLo(su.z), a5 = di * bfHi(su.z);
  float a6 = di * bfLo(su.w), a7 = di * bfHi(su.w);
  for (int base = e0 & ~1; base < e1; base += 4) {
    // two aligned int4 loads = 4 edge records (stale/tail records get nm=0;
    // their src fields are valid nodes or sentinels, so gathers stay in-bounds)
    int4 p0 = *(const int4*)(edges + base);
    int4 p1 = *(const int4*)(edges + base + 2);
    uint4 h0 = H8[(size_t)(unsigned)p0.x * 8u + ql];
    uint4 h1 = H8[(size_t)(unsigned)p0.z * 8u + ql];
    uint4 h2 = H8[(size_t)(unsigned)p1.x * 8u + ql];
    uint4 h3 = H8[(size_t)(unsigned)p1.z * 8u + ql];
    float n0 = (base >= e0) ? __int_as_float(p0.y) : 0.f;
    float n1 = (base + 1 < e1) ? __int_as_float(p0.w) : 0.f;
    float n2 = (base + 2 < e1) ? __int_as_float(p1.y) : 0.f;
    float n3 = (base + 3 < e1) ? __int_as_float(p1.w) : 0.f;
    a0 = fmaf(n0, bfLo(h0.x), a0); a1 = fmaf(n0, bfHi(h0.x), a1);
    a2 = fmaf(n0, bfLo(h0.y), a2); a3 = fmaf(n0, bfHi(h0.y), a3);
    a4 = fmaf(n0, bfLo(h0.z), a4); a5 = fmaf(n0, bfHi(h0.z), a5);
    a6 = fmaf(n0, bfLo(h0.w), a6); a7 = fmaf(n0, bfHi(h0.w), a7);
    a0 = fmaf(n1, bfLo(h1.x), a0); a1 = fmaf(n1, bfHi(h1.x), a1);
    a2 = fmaf(n1, bfLo(h1.y), a2); a3 = fmaf(n1, bfHi(h1.y), a3);
    a4 = fmaf(n1, bfLo(h1.z), a4); a5 = fmaf(n1, bfHi(h1.z), a5);
    a6 = fmaf(n1, bfLo(h1.w), a6); a7 = fmaf(n1, bfHi(h1.w), a7);
    a0 = fmaf(n2, bfLo(h2.x), a0); a1 = fmaf(n2, bfHi(h2.x), a1);
    a2 = fmaf(n2, bfLo(h2.y), a2); a3 = fmaf(n2, bfHi(h2.y), a3);
    a4 = fmaf(n2, bfLo(h2.z), a4); a5 = fmaf(n2, bfHi(h2.z), a5);
    a6 = fmaf(n2, bfLo(h2.w), a6); a7 = fmaf(n2, bfHi(h2.w), a7);
    a0 = fmaf(n3, bfLo(h3.x), a0); a1 = fmaf(n3, bfHi(h3.x), a1);
    a2 = fmaf(n3, bfLo(h3.y), a2); a3 = fmaf(n3, bfHi(h3.y), a3);
    a4 = fmaf(n3, bfLo(h3.z), a4); a5 = fmaf(n3, bfHi(h3.z), a5);
    a6 = fmaf(n3, bfLo(h3.w), a6); a7 = fmaf(n3, bfHi(h3.w), a7);
  }
  float4 bv0 = ((const float4*)bias)[2 * ql];
  float4 bv1 = ((const float4*)bias)[2 * ql + 1];
  a0 += bv0.x; a1 += bv0.y; a2 += bv0.z; a3 += bv0.w;
  a4 += bv1.x; a5 += bv1.y; a6 += bv1.z; a7 += bv1.w;
  if (OUT_BF16) {
    a0 = fmaxf(a0, 0.f); a1 = fmaxf(a1, 0.f); a2 = fmaxf(a2, 0.f); a3 = fmaxf(a3, 0.f);
    a4 = fmaxf(a4, 0.f); a5 = fmaxf(a5, 0.f); a6 = fmaxf(a6, 0.f); a7 = fmaxf(a7, 0.f);
    uint4 o;
    o.x = (unsigned)f2bf(a0) | ((unsigned)f2bf(a1) << 16);
    o.y = (unsigned)f2bf(a2) | ((unsigned)f2bf(a3) << 16);
    o.z = (unsigned)f2bf(a4) | ((unsigned)f2bf(a5) << 16);
    o.w = (unsigned)f2bf(a6) | ((unsigned)f2bf(a7) << 16);
    ((uint4*)outp)[(size_t)node * 8 + ql] = o;
  } else {
    float4 o0, o1;
    o0.x = a0; o0.y = a1; o0.z = a2; o0.w = a3;
    o1.x = a4; o1.y = a5; o1.z = a6; o1.w = a7;
    ((float4*)outp)[(size_t)node * 16 + 2 * ql] = o0;
    ((float4*)outp)[(size_t)node * 16 + 2 * ql + 1] = o1;
  }
}

extern "C" void kernel_launch(void* const* d_in, const int* in_sizes, int n_in,
                              void* d_out, int out_size, void* d_ws, size_t ws_size,
                              hipStream_t stream) {
  const float* x  = (const float*)d_in[0];
  const int*   ei = (const int*)d_in[1];
  const float* ew = (const float*)d_in[2];
  const float* W1 = (const float*)d_in[3];
  const float* b1 = (const float*)d_in[4];
  const float* W2 = (const float*)d_in[5];
  const float* b2 = (const float*)d_in[6];
  float* out = (float*)d_out;

  const int n  = in_sizes[0] / HID;   // 100000
  const int nE = in_sizes[2];         // 1000000
  const int* src = ei;
  const int* dst = ei + nE;

  const int B   = (n + NPB - 1) / NPB;                // 391 buckets
  const int ept = (nE + B * 256 - 1) / (B * 256);     // edges per thread in S1/S3

  auto align512 = [](size_t v) { return (v + 511) & ~(size_t)511; };
  char* ws = (char*)d_ws;
  size_t off = 0;
  float* dinv        = (float*)(ws + off); off += align512((size_t)n * 4);
  int*   rowStart    = (int*)  (ws + off); off += align512((size_t)(n + 1) * 4);
  unsigned int* bucketCnt = (unsigned int*)(ws + off); off += align512((size_t)B * 16 * 4);
  int*   bucketStart = (int*)  (ws + off); off += align512((size_t)(B + 1) * 4);
  int2*  edges       = (int2*) (ws + off); off += align512((size_t)nE * 8 + 64);  // +sentinels
  unsigned short* bufA = (unsigned short*)(ws + off); off += align512((size_t)n * HID * 2);
  unsigned short* bufB = (unsigned short*)(ws + off);

  // blockBase (B*B*4 ~ 612KB) + e8 (nE*8 = 8MB) alias onto bufA (12.8MB):
  // both dead before gemm1 writes bufA.
  unsigned int* blockBase = (unsigned int*)bufA;
  int2* e8 = (int2*)((char*)bufA + align512((size_t)B * B * 4));

  const int aggBlocks = (((n + 7) / 8) * 64 + 255) / 256;   // 8 nodes per wave

  // ---- CSR build: atomic-free counting sort by dst>>8 ----
  hipMemsetAsync(bucketCnt, 0, (size_t)B * 16 * 4, stream);
  k_hist<<<B, 256, 0, stream>>>(dst, bucketCnt, blockBase, B, ept, nE);
  k_bscan<<<1, 512, 0, stream>>>(bucketCnt, bucketStart, rowStart, edges, B, n, nE);
  k_bucket<<<B, 256, 0, stream>>>(src, dst, ew, bucketStart, blockBase, e8, B, ept, nE);
  k_degfill<<<B, NPB, 0, stream>>>(e8, bucketStart, dinv, rowStart, edges, n);

  // ---- layer 1 ----
  k_gemm64<float><<<2048, 256, 0, stream>>>(x, W1, dinv, bufA, n);
  k_agg8<1><<<aggBlocks, 256, 0, stream>>>(edges, rowStart, dinv,
                                           (const uint4*)bufA, b1, bufB, n);

  // ---- layer 2 ----
  k_gemm64<unsigned short><<<2048, 256, 0, stream>>>(bufB, W2, dinv, bufA, n);
  k_agg8<0><<<aggBlocks, 256, 0, stream>>>(edges, rowStart, dinv,
                                           (const uint4*)bufA, b2, out, n);
}

// Round 11
// 216.220 us; speedup vs baseline: 1.2663x; 1.0638x over previous
//
#include <hip/hip_runtime.h>

#define HID 64
#define NPB 256   // nodes per bucket (bucket = dst >> 8)
#define RCAP 13   // degfill register-cache records per thread (P(>13*256/bucket)~0)

typedef __attribute__((ext_vector_type(8))) short bf16x8;
typedef __attribute__((ext_vector_type(4))) float f32x4;

__device__ inline float bf2f(unsigned short u) {
  return __uint_as_float((unsigned int)u << 16);
}
__device__ inline unsigned short f2bf(float f) {
  unsigned int u = __float_as_uint(f);
  u += 0x7fff + ((u >> 16) & 1);  // round-to-nearest-even
  return (unsigned short)(u >> 16);
}
__device__ inline float bfLo(unsigned int u) { return __uint_as_float(u << 16); }
__device__ inline float bfHi(unsigned int u) { return __uint_as_float(u & 0xffff0000u); }

// ---- S1: per-block LDS histogram over buckets + padded-line global reservation ----
__global__ __launch_bounds__(256) void k_hist(const int* __restrict__ dst,
                                              unsigned int* __restrict__ bucketCnt,  // B*16 padded
                                              unsigned int* __restrict__ blockBase,  // [B][B]
                                              int B, int ept, int nE) {
  __shared__ unsigned int hist[512];
  for (int c = threadIdx.x; c < B; c += 256) hist[c] = 0;
  __syncthreads();
  int base = blockIdx.x * 256 * ept;
  for (int i = 0; i < ept; ++i) {
    int e = base + i * 256 + threadIdx.x;
    if (e < nE) atomicAdd(&hist[(unsigned)dst[e] >> 8], 1u);
  }
  __syncthreads();
  for (int c = threadIdx.x; c < B; c += 256) {
    unsigned int h = hist[c];
    unsigned int b = 0;
    if (h) b = atomicAdd(&bucketCnt[c * 16], h);  // 64B-padded: serial only per line
    blockBase[(size_t)blockIdx.x * B + c] = b;
  }
}

// ---- S2: exclusive scan of bucket totals (B <= 512); also writes edge sentinels ----
__global__ __launch_bounds__(512) void k_bscan(const unsigned int* __restrict__ bucketCnt,
                                               int* __restrict__ bucketStart,
                                               int* __restrict__ rowStart,
                                               int2* __restrict__ edges,
                                               int B, int n, int nE) {
  __shared__ int s[512];
  int v = (threadIdx.x < (unsigned)B) ? (int)bucketCnt[threadIdx.x * 16] : 0;
  s[threadIdx.x] = v;
  __syncthreads();
  for (int o = 1; o < 512; o <<= 1) {
    int t = (threadIdx.x >= (unsigned)o) ? s[threadIdx.x - o] : 0;
    __syncthreads();
    s[threadIdx.x] += t;
    __syncthreads();
  }
  if (threadIdx.x < (unsigned)B) bucketStart[threadIdx.x] = s[threadIdx.x] - v;
  if (threadIdx.x == 0) { bucketStart[B] = nE; rowStart[n] = nE; }
  if (threadIdx.x < 4) edges[nE + threadIdx.x] = make_int2(0, 0);  // safe tail reads
}

// ---- S3: scatter edges into bucket regions via LDS cursors ----
// record: {src | dLoc<<24, ew_bits}  (src < 2^24)
__global__ __launch_bounds__(256) void k_bucket(const int* __restrict__ src,
                                                const int* __restrict__ dst,
                                                const float* __restrict__ ew,
                                                const int* __restrict__ bucketStart,
                                                const unsigned int* __restrict__ blockBase,
                                                int2* __restrict__ e8,
                                                int B, int ept, int nE) {
  __shared__ int cursor[512];
  for (int c = threadIdx.x; c < B; c += 256)
    cursor[c] = bucketStart[c] + (int)blockBase[(size_t)blockIdx.x * B + c];
  __syncthreads();
  int base = blockIdx.x * 256 * ept;
  for (int i = 0; i < ept; ++i) {
    int e = base + i * 256 + threadIdx.x;
    if (e < nE) {
      int d = dst[e];
      int slot = atomicAdd(&cursor[d >> 8], 1);
      e8[slot] = make_int2(src[e] | ((d & 255) << 24), __float_as_int(ew[e]));
    }
  }
}

// ---- S4: FUSED deg + count + scan + fill, one kernel, ONE e8 read (records
// register-cached; strided overflow fallback). edges record: {src, ew*dinv[dst]} ----
__global__ __launch_bounds__(NPB) void k_degfill(const int2* __restrict__ e8,
                                                 const int* __restrict__ bucketStart,
                                                 float* __restrict__ dinv,
                                                 int* __restrict__ rowStart,
                                                 int2* __restrict__ edges, int n) {
  __shared__ float deg[NPB];
  __shared__ int cnt[NPB];
  __shared__ int s[NPB];
  deg[threadIdx.x] = 1.0f;  // self-loop weight
  cnt[threadIdx.x] = 0;
  __syncthreads();
  int c = blockIdx.x;
  int i0 = bucketStart[c], i1 = bucketStart[c + 1];
  int2 rec[RCAP];
  int myCnt = 0;
  for (int i = i0 + threadIdx.x; i < i1; i += NPB) {
    int2 r = e8[i];
#pragma unroll
    for (int k = 0; k < RCAP; ++k)
      if (k == myCnt) rec[k] = r;
    myCnt++;
    int l = (unsigned)r.x >> 24;
    atomicAdd(&deg[l], __int_as_float(r.y));
    atomicAdd(&cnt[l], 1);
  }
  __syncthreads();
  int v = cnt[threadIdx.x];
  s[threadIdx.x] = v;
  __syncthreads();
  for (int o = 1; o < NPB; o <<= 1) {
    int t = (threadIdx.x >= (unsigned)o) ? s[threadIdx.x - o] : 0;
    __syncthreads();
    s[threadIdx.x] += t;
    __syncthreads();
  }
  int rowBase = i0 + s[threadIdx.x] - v;
  float di = rsqrtf(deg[threadIdx.x]);
  int g = c * NPB + threadIdx.x;
  if (g < n) {
    rowStart[g] = rowBase;
    dinv[g] = di;
  }
  __syncthreads();             // all reads of deg/cnt/s done
  cnt[threadIdx.x] = rowBase;  // reuse as cursor
  deg[threadIdx.x] = di;       // reuse as ddst
  __syncthreads();
#pragma unroll
  for (int k = 0; k < RCAP; ++k) {
    if (k < myCnt) {
      int2 r = rec[k];
      int l = (unsigned)r.x >> 24;
      int pos = atomicAdd(&cnt[l], 1);
      float norm = __int_as_float(r.y) * deg[l];  // ew * dinv[dst]
      edges[pos] = make_int2(r.x & 0xFFFFFF, __float_as_int(norm));
    }
  }
  // overflow fallback (statistically never taken at E/B ~ 2560)
  for (int i = i0 + threadIdx.x + RCAP * NPB; i < i1; i += NPB) {
    int2 r = e8[i];
    int l = (unsigned)r.x >> 24;
    int pos = atomicAdd(&cnt[l], 1);
    float norm = __int_as_float(r.y) * deg[l];
    edges[pos] = make_int2(r.x & 0xFFFFFF, __float_as_int(norm));
  }
}

// ---- MFMA 64x64 projection, split-W (Wb + residual Wr, both bf16) for f32-grade
// weight precision. Out = bf16(dinv[row] * (X @ W)). A/B/D layouts per verified
// gfx950 16x16x32_bf16 mappings. ----
template <typename TI>
__global__ __launch_bounds__(256) void k_gemmMF(const TI* __restrict__ X,
                                                const float* __restrict__ W,
                                                const float* __restrict__ dinv,
                                                unsigned short* __restrict__ Out,
                                                int n, int nTiles) {
  int wv = threadIdx.x >> 6;
  int lane = threadIdx.x & 63;
  int m16 = lane & 15;   // A row within tile / B+D col
  int q = lane >> 4;     // quad: k-offset q*8 for A/B, row-offset q*4 for D
  // B fragments (held in VGPRs for the whole kernel): 4 n-tiles x 2 k-halves
  bf16x8 Bb[4][2], Br[4][2];
#pragma unroll
  for (int nt = 0; nt < 4; ++nt)
#pragma unroll
    for (int kh = 0; kh < 2; ++kh) {
      int ncol = nt * 16 + m16;
      int k0 = kh * 32 + q * 8;
#pragma unroll
      for (int j = 0; j < 8; ++j) {
        float w = W[(k0 + j) * HID + ncol];   // L1-hot after first touch (16 KB)
        unsigned short wb = f2bf(w);
        Bb[nt][kh][j] = (short)wb;
        Br[nt][kh][j] = (short)f2bf(w - bf2f(wb));
      }
    }
  for (int t = blockIdx.x; t < nTiles; t += gridDim.x) {
    int rowBase = t * 64 + wv * 16;
    if (rowBase >= n) continue;
    int mc = rowBase + m16;
    if (mc >= n) mc = n - 1;               // clamped load; stores guarded below
    bf16x8 A[2];
    if (sizeof(TI) == 2) {
      const unsigned short* Xp = (const unsigned short*)X + (size_t)mc * HID;
      A[0] = *(const bf16x8*)(Xp + q * 8);
      A[1] = *(const bf16x8*)(Xp + 32 + q * 8);
    } else {
      const float* Xp = (const float*)X + (size_t)mc * HID;
#pragma unroll
      for (int kh = 0; kh < 2; ++kh) {
        f32x4 x0 = *(const f32x4*)(Xp + kh * 32 + q * 8);
        f32x4 x1 = *(const f32x4*)(Xp + kh * 32 + q * 8 + 4);
#pragma unroll
        for (int j = 0; j < 4; ++j) {
          A[kh][j] = (short)f2bf(x0[j]);
          A[kh][4 + j] = (short)f2bf(x1[j]);
        }
      }
    }
    float dv[4];
#pragma unroll
    for (int r = 0; r < 4; ++r) {
      int rg = rowBase + q * 4 + r;
      dv[r] = dinv[rg < n ? rg : n - 1];
    }
#pragma unroll
    for (int nt = 0; nt < 4; ++nt) {
      f32x4 acc = {0.f, 0.f, 0.f, 0.f};
      acc = __builtin_amdgcn_mfma_f32_16x16x32_bf16(A[0], Bb[nt][0], acc, 0, 0, 0);
      acc = __builtin_amdgcn_mfma_f32_16x16x32_bf16(A[1], Bb[nt][1], acc, 0, 0, 0);
      acc = __builtin_amdgcn_mfma_f32_16x16x32_bf16(A[0], Br[nt][0], acc, 0, 0, 0);
      acc = __builtin_amdgcn_mfma_f32_16x16x32_bf16(A[1], Br[nt][1], acc, 0, 0, 0);
#pragma unroll
      for (int r = 0; r < 4; ++r) {
        int rg = rowBase + q * 4 + r;
        if (rg < n)
          Out[(size_t)rg * HID + nt * 16 + m16] = f2bf(acc[r] * dv[r]);
      }
    }
  }
}

// ---- CSR aggregate: 8 nodes per wave (8-lane group = node, lane covers 8
// channels via one uint4 = 128B row in ONE VMEM instr). Paired int4 edge loads. ----
template <int OUT_BF16>
__global__ __launch_bounds__(256) void k_agg8(const int2* __restrict__ edges,
                                              const int* __restrict__ rowStart,
                                              const float* __restrict__ dinv,
                                              const uint4* __restrict__ H8,  // 8 x uint4 per node
                                              const float* __restrict__ bias,
                                              void* __restrict__ outp, int n) {
  int gwave = (blockIdx.x * 256 + threadIdx.x) >> 6;
  int lane = threadIdx.x & 63;
  int q = lane >> 3;    // which of 8 nodes in this wave
  int ql = lane & 7;    // channels 8*ql .. 8*ql+7
  int node = gwave * 8 + q;
  if (node >= n) return;
  int e0 = rowStart[node];
  int e1 = rowStart[node + 1];
  float di = dinv[node];
  uint4 su = H8[(size_t)node * 8 + ql];
  float a0 = di * bfLo(su.x), a1 = di * bfHi(su.x);
  float a2 = di * bfLo(su.y), a3 = di * bfHi(su.y);
  float a4 = di * bfLo(su.z), a5 = di * bfHi(su.z);
  float a6 = di * bfLo(su.w), a7 = di * bfHi(su.w);
  for (int base = e0 & ~1; base < e1; base += 4) {
    int4 p0 = *(const int4*)(edges + base);
    int4 p1 = *(const int4*)(edges + base + 2);
    uint4 h0 = H8[(size_t)(unsigned)p0.x * 8u + ql];
    uint4 h1 = H8[(size_t)(unsigned)p0.z * 8u + ql];
    uint4 h2 = H8[(size_t)(unsigned)p1.x * 8u + ql];
    uint4 h3 = H8[(size_t)(unsigned)p1.z * 8u + ql];
    float n0 = (base >= e0) ? __int_as_float(p0.y) : 0.f;
    float n1 = (base + 1 < e1) ? __int_as_float(p0.w) : 0.f;
    float n2 = (base + 2 < e1) ? __int_as_float(p1.y) : 0.f;
    float n3 = (base + 3 < e1) ? __int_as_float(p1.w) : 0.f;
    a0 = fmaf(n0, bfLo(h0.x), a0); a1 = fmaf(n0, bfHi(h0.x), a1);
    a2 = fmaf(n0, bfLo(h0.y), a2); a3 = fmaf(n0, bfHi(h0.y), a3);
    a4 = fmaf(n0, bfLo(h0.z), a4); a5 = fmaf(n0, bfHi(h0.z), a5);
    a6 = fmaf(n0, bfLo(h0.w), a6); a7 = fmaf(n0, bfHi(h0.w), a7);
    a0 = fmaf(n1, bfLo(h1.x), a0); a1 = fmaf(n1, bfHi(h1.x), a1);
    a2 = fmaf(n1, bfLo(h1.y), a2); a3 = fmaf(n1, bfHi(h1.y), a3);
    a4 = fmaf(n1, bfLo(h1.z), a4); a5 = fmaf(n1, bfHi(h1.z), a5);
    a6 = fmaf(n1, bfLo(h1.w), a6); a7 = fmaf(n1, bfHi(h1.w), a7);
    a0 = fmaf(n2, bfLo(h2.x), a0); a1 = fmaf(n2, bfHi(h2.x), a1);
    a2 = fmaf(n2, bfLo(h2.y), a2); a3 = fmaf(n2, bfHi(h2.y), a3);
    a4 = fmaf(n2, bfLo(h2.z), a4); a5 = fmaf(n2, bfHi(h2.z), a5);
    a6 = fmaf(n2, bfLo(h2.w), a6); a7 = fmaf(n2, bfHi(h2.w), a7);
    a0 = fmaf(n3, bfLo(h3.x), a0); a1 = fmaf(n3, bfHi(h3.x), a1);
    a2 = fmaf(n3, bfLo(h3.y), a2); a3 = fmaf(n3, bfHi(h3.y), a3);
    a4 = fmaf(n3, bfLo(h3.z), a4); a5 = fmaf(n3, bfHi(h3.z), a5);
    a6 = fmaf(n3, bfLo(h3.w), a6); a7 = fmaf(n3, bfHi(h3.w), a7);
  }
  float4 bv0 = ((const float4*)bias)[2 * ql];
  float4 bv1 = ((const float4*)bias)[2 * ql + 1];
  a0 += bv0.x; a1 += bv0.y; a2 += bv0.z; a3 += bv0.w;
  a4 += bv1.x; a5 += bv1.y; a6 += bv1.z; a7 += bv1.w;
  if (OUT_BF16) {
    a0 = fmaxf(a0, 0.f); a1 = fmaxf(a1, 0.f); a2 = fmaxf(a2, 0.f); a3 = fmaxf(a3, 0.f);
    a4 = fmaxf(a4, 0.f); a5 = fmaxf(a5, 0.f); a6 = fmaxf(a6, 0.f); a7 = fmaxf(a7, 0.f);
    uint4 o;
    o.x = (unsigned)f2bf(a0) | ((unsigned)f2bf(a1) << 16);
    o.y = (unsigned)f2bf(a2) | ((unsigned)f2bf(a3) << 16);
    o.z = (unsigned)f2bf(a4) | ((unsigned)f2bf(a5) << 16);
    o.w = (unsigned)f2bf(a6) | ((unsigned)f2bf(a7) << 16);
    ((uint4*)outp)[(size_t)node * 8 + ql] = o;
  } else {
    float4 o0, o1;
    o0.x = a0; o0.y = a1; o0.z = a2; o0.w = a3;
    o1.x = a4; o1.y = a5; o1.z = a6; o1.w = a7;
    ((float4*)outp)[(size_t)node * 16 + 2 * ql] = o0;
    ((float4*)outp)[(size_t)node * 16 + 2 * ql + 1] = o1;
  }
}

extern "C" void kernel_launch(void* const* d_in, const int* in_sizes, int n_in,
                              void* d_out, int out_size, void* d_ws, size_t ws_size,
                              hipStream_t stream) {
  const float* x  = (const float*)d_in[0];
  const int*   ei = (const int*)d_in[1];
  const float* ew = (const float*)d_in[2];
  const float* W1 = (const float*)d_in[3];
  const float* b1 = (const float*)d_in[4];
  const float* W2 = (const float*)d_in[5];
  const float* b2 = (const float*)d_in[6];
  float* out = (float*)d_out;

  const int n  = in_sizes[0] / HID;   // 100000
  const int nE = in_sizes[2];         // 1000000
  const int* src = ei;
  const int* dst = ei + nE;

  const int B   = (n + NPB - 1) / NPB;                // 391 buckets
  const int ept = (nE + B * 256 - 1) / (B * 256);     // edges per thread in S1/S3

  auto align512 = [](size_t v) { return (v + 511) & ~(size_t)511; };
  char* ws = (char*)d_ws;
  size_t off = 0;
  float* dinv        = (float*)(ws + off); off += align512((size_t)n * 4);
  int*   rowStart    = (int*)  (ws + off); off += align512((size_t)(n + 1) * 4);
  unsigned int* bucketCnt = (unsigned int*)(ws + off); off += align512((size_t)B * 16 * 4);
  int*   bucketStart = (int*)  (ws + off); off += align512((size_t)(B + 1) * 4);
  int2*  edges       = (int2*) (ws + off); off += align512((size_t)nE * 8 + 64);  // +sentinels
  unsigned short* bufA = (unsigned short*)(ws + off); off += align512((size_t)n * HID * 2);
  unsigned short* bufB = (unsigned short*)(ws + off);

  // blockBase (B*B*4 ~ 612KB) + e8 (nE*8 = 8MB) alias onto bufA (12.8MB):
  // both dead before gemm1 writes bufA.
  unsigned int* blockBase = (unsigned int*)bufA;
  int2* e8 = (int2*)((char*)bufA + align512((size_t)B * B * 4));

  const int aggBlocks = (((n + 7) / 8) * 64 + 255) / 256;   // 8 nodes per wave
  const int nTiles = (n + 63) / 64;                          // 64-row gemm tiles

  // ---- CSR build: atomic-free counting sort by dst>>8 ----
  hipMemsetAsync(bucketCnt, 0, (size_t)B * 16 * 4, stream);
  k_hist<<<B, 256, 0, stream>>>(dst, bucketCnt, blockBase, B, ept, nE);
  k_bscan<<<1, 512, 0, stream>>>(bucketCnt, bucketStart, rowStart, edges, B, n, nE);
  k_bucket<<<B, 256, 0, stream>>>(src, dst, ew, bucketStart, blockBase, e8, B, ept, nE);
  k_degfill<<<B, NPB, 0, stream>>>(e8, bucketStart, dinv, rowStart, edges, n);

  // ---- layer 1 ----
  k_gemmMF<float><<<256, 256, 0, stream>>>(x, W1, dinv, bufA, n, nTiles);
  k_agg8<1><<<aggBlocks, 256, 0, stream>>>(edges, rowStart, dinv,
                                           (const uint4*)bufA, b1, bufB, n);

  // ---- layer 2 ----
  k_gemmMF<unsigned short><<<256, 256, 0, stream>>>(bufB, W2, dinv, bufA, n, nTiles);
  k_agg8<0><<<aggBlocks, 256, 0, stream>>>(edges, rowStart, dinv,
                                           (const uint4*)bufA, b2, out, n);
}